// Round 2
// 671.373 us; speedup vs baseline: 1.2340x; 1.2340x over previous
//
#include <hip/hip_runtime.h>

#define NSMP 8192
#define INW  8712   // input row stride (floats)
#define OUTW 8448   // output row stride (floats)
#define AOFF 512    // column offset of A block inside input
#define DO   256    // DOUT

typedef __attribute__((ext_vector_type(4)))  float f32x4;
typedef __attribute__((ext_vector_type(8)))  short short8;
typedef __attribute__((ext_vector_type(16))) float floatx16;

typedef __attribute__((address_space(1))) const unsigned int* gptr_t;
typedef __attribute__((address_space(3)))       unsigned int* lptr_t;

// pack two fp32 -> two bf16 (truncation; same numerics as the 828us version)
__device__ __forceinline__ unsigned pk_bf16(float lo, float hi) {
    return (__float_as_uint(lo) >> 16) | (__float_as_uint(hi) & 0xffff0000u);
}

// async global->LDS, 16B per lane; LDS dest = wave-uniform base + lane*16
__device__ __forceinline__ void gload_lds16(const void* g, void* l) {
    __builtin_amdgcn_global_load_lds((gptr_t)g, (lptr_t)l, 16, 0, 0);
}

// ---------------- Kernel A: copy A+I to out[:,256:], column sums -> d ----------
// 32-row tiles -> 2048 blocks (full occupancy). NT stores keep input-A in L3 for kmm.
__global__ __launch_bounds__(256) void kcopy(const float* __restrict__ in,
                                             float* __restrict__ out,
                                             float* __restrict__ d) {
    const int t  = threadIdx.x;
    const int j0 = blockIdx.x * 1024;   // 8 col tiles of 1024
    const int i0 = blockIdx.y * 32;     // 256 row tiles of 32
    const int jc = j0 + 4 * t;
    const float* src = in  + (size_t)i0 * INW  + AOFF + jc;
    float*       dst = out + (size_t)i0 * OUTW + DO   + jc;
    f32x4 cs = {0.f, 0.f, 0.f, 0.f};
#pragma unroll 8
    for (int r = 0; r < 32; ++r) {
        f32x4 v = *(const f32x4*)(src + (size_t)r * INW);
        int di = (i0 + r) - j0;                       // diagonal col within tile
        if ((di >> 2) == t) {                         // di<0 -> negative >> stays negative
            int s = di & 3;
            v[0] += (s == 0); v[1] += (s == 1); v[2] += (s == 2); v[3] += (s == 3);
        }
        cs += v;
        __builtin_nontemporal_store(v, (f32x4*)(dst + (size_t)r * OUTW));  // don't pollute L3
    }
    atomicAdd(&d[jc + 0], cs[0]);
    atomicAdd(&d[jc + 1], cs[1]);
    atomicAdd(&d[jc + 2], cs[2]);
    atomicAdd(&d[jc + 3], cs[3]);
}

// ------- Kernel B: support = X@W, write s' packed k-major: sP[oct=k/8][col][k%8] ----
// (layout so kmm's B staging is fully contiguous 1KB per wave-issue)
__global__ __launch_bounds__(256) void ksupport(const float* __restrict__ in,
                                                const float* __restrict__ w,
                                                const float* __restrict__ d,
                                                float* __restrict__ dinv,
                                                unsigned short* __restrict__ sP) {
    const int c  = threadIdx.x;          // output column 0..255
    const int r0 = blockIdx.x * 8;       // 8 support-rows per block = one k-octet
    const float* X = in + (size_t)r0 * INW;   // X = input[:, :512]
    float acc[8] = {0.f, 0.f, 0.f, 0.f, 0.f, 0.f, 0.f, 0.f};
#pragma unroll 4
    for (int k = 0; k < 512; ++k) {
        float wv = w[(size_t)k * DO + c];
#pragma unroll
        for (int r = 0; r < 8; ++r)
            acc[r] = fmaf(X[(size_t)r * INW + k], wv, acc[r]);  // X load wave-uniform -> s_load
    }
    union { unsigned short h[8]; uint4 u; } pk;
#pragma unroll
    for (int r = 0; r < 8; ++r) {
        float dv = rsqrtf(d[r0 + r]);
        unsigned ub = __float_as_uint(acc[r] * dv);
        ub += 0x7fffu + ((ub >> 16) & 1u);            // RNE to bf16
        pk.h[r] = (unsigned short)(ub >> 16);
    }
    // sP[r0/8][c][0..7], 16B/thread, 4KB contiguous per block
    *(uint4*)(sP + (size_t)(r0 >> 3) * (DO * 8) + (size_t)c * 8) = pk.u;
    if (c < 8) dinv[r0 + c] = rsqrtf(d[r0 + c]);
}

// ---------------- Kernel C: out[:, :256] = dinv_i * (A0 @ s' + s'_i) -----------
// LDS-staged, double-buffered (T3 2-phase): A fp32 32x64 XOR-swizzled granules,
// B bf16 8x128x8 linear. BM=32, BN=128, BK=64; 512 blocks, 4 waves, 48KB LDS.
__global__ __launch_bounds__(256, 2) void kmm(const float* __restrict__ in,
                                              const unsigned short* __restrict__ sP,
                                              const float* __restrict__ dinv,
                                              float* __restrict__ out) {
    __shared__ __align__(16) float          lA[2][32 * 64];      // 8 KB per buffer
    __shared__ __align__(16) unsigned short lB[2][8 * 128 * 8];  // 16 KB per buffer

    const int b  = blockIdx.x;
    // XCD-pair swizzle: blocks b and b+8 (same rg, ch=0/1) land on the same XCD (b%8)
    const int rg = ((b >> 4) << 3) + (b & 7);   // 0..255 row group
    const int ch = (b >> 3) & 1;                // column half
    const int tid = threadIdx.x;
    const int w = tid >> 6, lane = tid & 63;
    const int m = lane & 31, q = lane >> 5;
    const int i0 = rg * 32;
    const int cc = ch * 128 + w * 32 + m;

    // A staging geometry: wave w loads rows w*8..w*8+7 (2 issues x 4 rows x 16 lanes)
    const int subr = lane >> 4;            // row within a 4-row issue
    const int gl   = lane & 15;            // LDS granule slot (16B) within row
    const int lrA0 = w * 8;

    floatx16 acc;
#pragma unroll
    for (int z = 0; z < 16; ++z) acc[z] = 0.f;

    auto stage = [&](int nb, int s) {
        const int k0 = s * 64;
        // A: LDS dest LINEAR, global source INVERSE-swizzled (slot gl gets global
        // granule gl^(row&7)); ds_read applies the same XOR -> conflict-free + correct.
#pragma unroll
        for (int t = 0; t < 2; ++t) {
            const int lr = lrA0 + t * 4 + subr;
            const float* g = in + (size_t)(i0 + lr) * INW + AOFF + k0 + 4 * (gl ^ (lr & 7));
            gload_lds16(g, &lA[nb][(lrA0 + t * 4) * 64]);
        }
        // B: fully contiguous 1KB per issue; wave w covers octets 2w, 2w+1
#pragma unroll
        for (int j = 0; j < 4; ++j) {
            const int oct  = 2 * w + (j >> 1);
            const int ch64 = j & 1;
            const unsigned short* g = sP + (size_t)(s * 8 + oct) * (DO * 8)
                                        + (size_t)(ch * 128 + ch64 * 64 + lane) * 8;
            gload_lds16(g, &lB[nb][(oct * 128 + ch64 * 64) * 8]);
        }
    };

    stage(0, 0);
    __syncthreads();

    for (int s = 0; s < 128; ++s) {
        const int cur = s & 1;
        if (s + 1 < 128) stage(cur ^ 1, s + 1);   // issue next-tile loads BEFORE compute
        const float*          lAc = lA[cur];
        const unsigned short* lBc = lB[cur];
#pragma unroll
        for (int ks = 0; ks < 4; ++ks) {
            const int gbase = ks * 4 + q * 2;
            const int g0 = gbase ^ (m & 7);           // swizzled granule slots
            const int g1 = (gbase + 1) ^ (m & 7);
            f32x4 a0 = *(const f32x4*)(lAc + m * 64 + g0 * 4);
            f32x4 a1 = *(const f32x4*)(lAc + m * 64 + g1 * 4);
            uint4 bq = *(const uint4*)(lBc + ((size_t)(2 * ks + q) * 128 + w * 32 + m) * 8);
            union { unsigned u[4]; short8 s8; } fa;
            fa.u[0] = pk_bf16(a0[0], a0[1]); fa.u[1] = pk_bf16(a0[2], a0[3]);
            fa.u[2] = pk_bf16(a1[0], a1[1]); fa.u[3] = pk_bf16(a1[2], a1[3]);
            union { uint4 q4; short8 s8; } fb; fb.q4 = bq;
            acc = __builtin_amdgcn_mfma_f32_32x32x16_bf16(fa.s8, fb.s8, acc, 0, 0, 0);
        }
        __syncthreads();   // drains vmcnt+lgkmcnt -> next buffer ready, this one reusable
    }

    // epilogue: D row = (reg&3) + 8*(reg>>2) + 4*q, col = lane&31 (HW-verified layout)
#pragma unroll
    for (int g = 0; g < 4; ++g) {
        const ushort4 s4 = *(const ushort4*)(sP + (size_t)(i0 / 8 + g) * (DO * 8)
                                                + (size_t)cc * 8 + 4 * q);
        unsigned short sv[4] = {s4.x, s4.y, s4.z, s4.w};
#pragma unroll
        for (int rr = 0; rr < 4; ++rr) {
            const int row = i0 + 8 * g + 4 * q + rr;
            const float idt = __uint_as_float(((unsigned)sv[rr]) << 16);  // +I contribution, fp32
            out[(size_t)row * OUTW + cc] = (acc[g * 4 + rr] + idt) * dinv[row];
        }
    }
}

extern "C" void kernel_launch(void* const* d_in, const int* in_sizes, int n_in,
                              void* d_out, int out_size, void* d_ws, size_t ws_size,
                              hipStream_t stream) {
    (void)in_sizes; (void)n_in; (void)out_size; (void)ws_size;
    const float* in = (const float*)d_in[0];
    const float* w  = (const float*)d_in[1];
    float* out  = (float*)d_out;
    float* d    = (float*)d_ws;                       // 8192 f32 column sums
    float* dinv = d + NSMP;                           // 8192 f32
    unsigned short* sP = (unsigned short*)(d + 2 * NSMP);  // packed s': 1024 x 256 x 8 bf16 (4 MB)

    hipMemsetAsync(d, 0, NSMP * sizeof(float), stream);
    kcopy<<<dim3(8, 256), 256, 0, stream>>>(in, out, d);
    ksupport<<<1024, 256, 0, stream>>>(in, w, d, dinv, sP);
    kmm<<<512, 256, 0, stream>>>(in, sP, dinv, out);
}

// Round 3
// 624.076 us; speedup vs baseline: 1.3275x; 1.0758x over previous
//
#include <hip/hip_runtime.h>

#define NSMP 8192
#define INW  8712   // input row stride (floats)
#define OUTW 8448   // output row stride (floats)
#define AOFF 512    // column offset of A block inside input
#define DO   256    // DOUT

typedef __attribute__((ext_vector_type(4)))  float f32x4;
typedef __attribute__((ext_vector_type(8)))  short short8;
typedef __attribute__((ext_vector_type(16))) float floatx16;

typedef __attribute__((address_space(1))) const unsigned int* gptr_t;
typedef __attribute__((address_space(3)))       unsigned int* lptr_t;

// pack two fp32 -> two bf16 (truncation; numerics identical to prior passing versions)
__device__ __forceinline__ unsigned pk_bf16(float lo, float hi) {
    return (__float_as_uint(lo) >> 16) | (__float_as_uint(hi) & 0xffff0000u);
}

// async global->LDS, 16B per lane; LDS dest = wave-uniform base + lane*16
__device__ __forceinline__ void gload_lds16(const void* g, void* l) {
    __builtin_amdgcn_global_load_lds((gptr_t)g, (lptr_t)l, 16, 0, 0);
}

// ------ Kernel A: copy A+I to out[:,256:], col sums -> d, bf16 A -> aP ---------
// NT loads (in-A read exactly once now) + NT stores for out (never re-read);
// aP stored normally so it sits in L3 for kmm.
__global__ __launch_bounds__(256) void kcopy(const float* __restrict__ in,
                                             float* __restrict__ out,
                                             float* __restrict__ d,
                                             unsigned short* __restrict__ aP) {
    const int t  = threadIdx.x;
    const int j0 = blockIdx.x * 1024;   // 8 col tiles of 1024
    const int i0 = blockIdx.y * 32;     // 256 row tiles of 32
    const int jc = j0 + 4 * t;
    const float*    src = in  + (size_t)i0 * INW  + AOFF + jc;
    float*          dst = out + (size_t)i0 * OUTW + DO   + jc;
    unsigned short* ap  = aP  + (size_t)i0 * NSMP + jc;
    f32x4 cs = {0.f, 0.f, 0.f, 0.f};
#pragma unroll 8
    for (int r = 0; r < 32; ++r) {
        f32x4 v = __builtin_nontemporal_load((const f32x4*)(src + (size_t)r * INW));
        uint2 pb;                                     // raw A (no +I) in bf16 for kmm
        pb.x = pk_bf16(v[0], v[1]);
        pb.y = pk_bf16(v[2], v[3]);
        *(uint2*)(ap + (size_t)r * NSMP) = pb;
        int di = (i0 + r) - j0;                       // diagonal col within tile
        if ((di >> 2) == t) {
            int s = di & 3;
            v[0] += (s == 0); v[1] += (s == 1); v[2] += (s == 2); v[3] += (s == 3);
        }
        cs += v;
        __builtin_nontemporal_store(v, (f32x4*)(dst + (size_t)r * OUTW));
    }
    atomicAdd(&d[jc + 0], cs[0]);
    atomicAdd(&d[jc + 1], cs[1]);
    atomicAdd(&d[jc + 2], cs[2]);
    atomicAdd(&d[jc + 3], cs[3]);
}

// ------- Kernel B: support = X@W, write s' packed k-major: sP[oct=k/8][col][k%8] ----
__global__ __launch_bounds__(256) void ksupport(const float* __restrict__ in,
                                                const float* __restrict__ w,
                                                const float* __restrict__ d,
                                                float* __restrict__ dinv,
                                                unsigned short* __restrict__ sP) {
    const int c  = threadIdx.x;          // output column 0..255
    const int r0 = blockIdx.x * 8;       // 8 support-rows per block = one k-octet
    const float* X = in + (size_t)r0 * INW;   // X = input[:, :512]
    float acc[8] = {0.f, 0.f, 0.f, 0.f, 0.f, 0.f, 0.f, 0.f};
#pragma unroll 4
    for (int k = 0; k < 512; ++k) {
        float wv = w[(size_t)k * DO + c];
#pragma unroll
        for (int r = 0; r < 8; ++r)
            acc[r] = fmaf(X[(size_t)r * INW + k], wv, acc[r]);  // X load wave-uniform -> s_load
    }
    union { unsigned short h[8]; uint4 u; } pk;
#pragma unroll
    for (int r = 0; r < 8; ++r) {
        float dv = rsqrtf(d[r0 + r]);
        unsigned ub = __float_as_uint(acc[r] * dv);
        ub += 0x7fffu + ((ub >> 16) & 1u);            // RNE to bf16
        pk.h[r] = (unsigned short)(ub >> 16);
    }
    *(uint4*)(sP + (size_t)(r0 >> 3) * (DO * 8) + (size_t)c * 8) = pk.u;
    if (c < 8) dinv[r0 + c] = rsqrtf(d[r0 + c]);
}

// ---------------- Kernel C: out[:, :256] = dinv_i * (A0 @ s' + s'_i) -----------
// A: bf16 from aP via gload_lds (XOR-swizzled source, linear LDS, 4KB/buf dbuf).
// B: direct global->register from L2-resident sP (fully coalesced), named dbl set.
// BM=32, BN=128, BK=64; 512 blocks, 4 waves; 8KB LDS total.
__global__ __launch_bounds__(256, 2) void kmm(const unsigned short* __restrict__ aP,
                                              const unsigned short* __restrict__ sP,
                                              const float* __restrict__ dinv,
                                              float* __restrict__ out) {
    __shared__ __align__(16) unsigned short lA[2][32 * 64];   // 4 KB per buffer

    const int b  = blockIdx.x;
    // XCD-pair swizzle: blocks b and b+8 (same rg, ch=0/1) land on the same XCD (b%8)
    const int rg = ((b >> 4) << 3) + (b & 7);   // 0..255 row group
    const int ch = (b >> 3) & 1;                // column half
    const int tid = threadIdx.x;
    const int w = tid >> 6, lane = tid & 63;
    const int m = lane & 31, q = lane >> 5;
    const int i0 = rg * 32;
    const int cc = ch * 128 + w * 32 + m;

    // A staging: wave w stages rows w*8..w*8+7; lane -> (row = l>>3, granule = l&7);
    // global source pre-swizzled (slot g holds granule g^(row&7)) -> swizzled ds_read OK
    const int srow = lane >> 3;
    const int sg   = lane & 7;
    const unsigned short* aSrc = aP + (size_t)(i0 + w * 8 + srow) * NSMP
                                    + 8 * (sg ^ (srow & 7));
    const unsigned short* bB   = sP + (size_t)q * 2048 + (size_t)cc * 8;

    floatx16 acc;
#pragma unroll
    for (int z = 0; z < 16; ++z) acc[z] = 0.f;

    uint4 Ba0, Ba1, Ba2, Ba3, Bb0, Bb1, Bb2, Bb3;

#define STAGE_A(nb, s) gload_lds16(aSrc + (size_t)(s) * 64, &lA[nb][w * 512])
#define LOAD_B(P, s) do {                                              \
        P##0 = *(const uint4*)(bB + (size_t)((s) * 8 + 0) * 2048);     \
        P##1 = *(const uint4*)(bB + (size_t)((s) * 8 + 2) * 2048);     \
        P##2 = *(const uint4*)(bB + (size_t)((s) * 8 + 4) * 2048);     \
        P##3 = *(const uint4*)(bB + (size_t)((s) * 8 + 6) * 2048);     \
    } while (0)
#define MFMA_KS(cur, Breg, ks) do {                                    \
        union { uint4 u; short8 s8; } fb_; fb_.u = Breg;               \
        const short8 af_ = *(const short8*)(                           \
            &lA[cur][m * 64 + ((((ks) * 2 + q) ^ (m & 7)) * 8)]);      \
        acc = __builtin_amdgcn_mfma_f32_32x32x16_bf16(af_, fb_.s8, acc, 0, 0, 0); \
    } while (0)
#define COMPUTE(cur, P) do {                                           \
        MFMA_KS(cur, P##0, 0); MFMA_KS(cur, P##1, 1);                  \
        MFMA_KS(cur, P##2, 2); MFMA_KS(cur, P##3, 3);                  \
    } while (0)

    STAGE_A(0, 0);
    LOAD_B(Ba, 0);
    __syncthreads();

    for (int s = 0; s < 128; s += 2) {
        STAGE_A(1, s + 1);                    // prefetch issued before compute
        LOAD_B(Bb, s + 1);
        COMPUTE(0, Ba);
        __syncthreads();                      // drains vmcnt -> buf1 + Bb ready
        const int s2 = (s + 2 < 128) ? s + 2 : 0;   // clamped; last-iter values unused
        STAGE_A(0, s2);
        LOAD_B(Ba, s2);
        COMPUTE(1, Bb);
        __syncthreads();
    }

#undef STAGE_A
#undef LOAD_B
#undef MFMA_KS
#undef COMPUTE

    // epilogue: D row = (reg&3) + 8*(reg>>2) + 4*q, col = lane&31 (HW-verified layout)
#pragma unroll
    for (int g = 0; g < 4; ++g) {
        const ushort4 s4 = *(const ushort4*)(sP + (size_t)(i0 / 8 + g) * (DO * 8)
                                                + (size_t)cc * 8 + 4 * q);
        unsigned short sv[4] = {s4.x, s4.y, s4.z, s4.w};
#pragma unroll
        for (int rr = 0; rr < 4; ++rr) {
            const int row = i0 + 8 * g + 4 * q + rr;
            const float idt = __uint_as_float(((unsigned)sv[rr]) << 16);  // +I contribution
            out[(size_t)row * OUTW + cc] = (acc[g * 4 + rr] + idt) * dinv[row];
        }
    }
}

extern "C" void kernel_launch(void* const* d_in, const int* in_sizes, int n_in,
                              void* d_out, int out_size, void* d_ws, size_t ws_size,
                              hipStream_t stream) {
    (void)in_sizes; (void)n_in; (void)out_size; (void)ws_size;
    const float* in = (const float*)d_in[0];
    const float* w  = (const float*)d_in[1];
    float* out  = (float*)d_out;
    float* d    = (float*)d_ws;                            // 8192 f32 column sums
    float* dinv = d + NSMP;                                // 8192 f32
    unsigned short* sP = (unsigned short*)(d + 2 * NSMP);  // 1024 x 256 x 8 bf16 (4 MB)
    unsigned short* aP = sP + (size_t)1024 * DO * 8;       // 8192 x 8192 bf16 (128 MB)

    hipMemsetAsync(d, 0, NSMP * sizeof(float), stream);
    kcopy<<<dim3(8, 256), 256, 0, stream>>>(in, out, d, aP);
    ksupport<<<1024, 256, 0, stream>>>(in, w, d, dinv, sP);
    kmm<<<512, 256, 0, stream>>>(aP, sP, dinv, out);
}